// Round 6
// baseline (48.101 us; speedup 1.0000x reference)
//
#include <hip/hip_runtime.h>
#include <math.h>

#define BATCH  512
#define SEQL   2048
#define NPTS   (SEQL*3)        // 6144 points per batch
#define NFLT   (NPTS*3)        // 18432 floats per batch per tensor
#define NGRP   (NPTS/4)        // 1536 groups of 4 points
#define SLICES 3
#define GPS    (NGRP/SLICES)   // 512 groups per slice
#define TPB    512
#define NWAVE  (TPB/64)
#define PSTRIDE 20             // floats per partial/param record

// ---------------- mask dtype handling ----------------
// flag: 0 = int32 {0,1}, 1 = uint8 {0,1}, 2 = float32
__device__ __forceinline__ int detect_flag(const void* cm, int* slds) {
    unsigned int v = ((const unsigned int*)cm)[threadIdx.x & 255];
    bool vi = (v <= 1u);
    bool vb = ((v & 0xFEFEFEFEu) == 0u);
    bool wi = __all(vi);
    bool wb = __all(vb);
    int wid = threadIdx.x >> 6;
    if ((threadIdx.x & 63) == 0) slds[wid] = (wi ? 1 : 0) | (wb ? 2 : 0);
    __syncthreads();
    if (threadIdx.x == 0) {
        int m = 3;
        for (int w = 0; w < (int)(blockDim.x >> 6); ++w) m &= slds[w];
        slds[8] = (m & 1) ? 0 : ((m & 2) ? 1 : 2);
    }
    __syncthreads();
    return slds[8];
}

__device__ __forceinline__ void load_mask4(const void* m, int flag, size_t g, float* w) {
    if (flag == 1) {
        unsigned int v = ((const unsigned int*)m)[g];
        w[0] = (v & 0x000000FFu) ? 1.f : 0.f;
        w[1] = (v & 0x0000FF00u) ? 1.f : 0.f;
        w[2] = (v & 0x00FF0000u) ? 1.f : 0.f;
        w[3] = (v & 0xFF000000u) ? 1.f : 0.f;
    } else if (flag == 0) {
        int4 v = ((const int4*)m)[g];
        w[0] = v.x ? 1.f : 0.f; w[1] = v.y ? 1.f : 0.f;
        w[2] = v.z ? 1.f : 0.f; w[3] = v.w ? 1.f : 0.f;
    } else {
        float4 v = ((const float4*)m)[g];
        w[0] = v.x != 0.f ? 1.f : 0.f; w[1] = v.y != 0.f ? 1.f : 0.f;
        w[2] = v.z != 0.f ? 1.f : 0.f; w[3] = v.w != 0.f ? 1.f : 0.f;
    }
}

// ---------------- reduction ----------------
template <int K>
__device__ __forceinline__ void block_reduce(float* acc, float* lds) {
#pragma unroll
    for (int k = 0; k < K; ++k) {
#pragma unroll
        for (int off = 32; off > 0; off >>= 1)
            acc[k] += __shfl_down(acc[k], off, 64);
    }
    int lane = threadIdx.x & 63;
    int wid  = threadIdx.x >> 6;
    if (lane == 0) {
#pragma unroll
        for (int k = 0; k < K; ++k) lds[wid * K + k] = acc[k];
    }
    __syncthreads();
    if (threadIdx.x == 0) {
#pragma unroll
        for (int k = 0; k < K; ++k) {
            float s = 0.f;
#pragma unroll
            for (int w = 0; w < NWAVE; ++w) s += lds[w * K + k];
            acc[k] = s;
        }
    }
}

__device__ __forceinline__ void accum_pt(float* a, float w,
                                         float px, float py, float pz,
                                         float qx, float qy, float qz) {
    a[0] += w;
    float wpx = w * px, wpy = w * py, wpz = w * pz;
    a[1] += wpx; a[2] += wpy; a[3] += wpz;
    a[4] += w * qx; a[5] += w * qy; a[6] += w * qz;
    a[7]  += wpx * qx; a[8]  += wpx * qy; a[9]  += wpx * qz;
    a[10] += wpy * qx; a[11] += wpy * qy; a[12] += wpy * qz;
    a[13] += wpz * qx; a[14] += wpz * qy; a[15] += wpz * qz;
}

// ---------------- pass A: per-(batch,slice) partial sums ----------------
// part[blk*PSTRIDE + 0..16]: cnt, sum wP(3), sum wQ(3), sum wPiQj(9), rescnt
__global__ __launch_bounds__(TPB) void k_sumsA(
    const float* __restrict__ P, const float* __restrict__ Q,
    const void* __restrict__ cmask, const void* __restrict__ rmask,
    float* __restrict__ part) {
    int blk = blockIdx.x;
    int b = blk / SLICES, slice = blk % SLICES;
    __shared__ int slds[9];
    __shared__ float lds[NWAVE * 17];
    int flag = detect_flag(cmask, slds);

    const float4* Pv = (const float4*)(P + (size_t)b * NFLT);
    const float4* Qv = (const float4*)(Q + (size_t)b * NFLT);
    int g = slice * GPS + threadIdx.x;          // group in batch

    float4 p0 = Pv[3 * g + 0], p1 = Pv[3 * g + 1], p2 = Pv[3 * g + 2];
    float4 q0 = Qv[3 * g + 0], q1 = Qv[3 * g + 1], q2 = Qv[3 * g + 2];
    float w[4];
    load_mask4(cmask, flag, (size_t)b * NGRP + g, w);

    float acc[17];
#pragma unroll
    for (int k = 0; k < 17; ++k) acc[k] = 0.0f;

    if (slice == 0) {   // residue count: SEQL/4 = 512 word-groups, one per thread
        size_t rg = (size_t)b * (SEQL / 4) + threadIdx.x;
        if (flag == 1) {
            unsigned int v = ((const unsigned int*)rmask)[rg];
            acc[16] = (float)__popc(v);
        } else if (flag == 0) {
            int4 v = ((const int4*)rmask)[rg];
            acc[16] = (v.x ? 1.f : 0.f) + (v.y ? 1.f : 0.f) + (v.z ? 1.f : 0.f) + (v.w ? 1.f : 0.f);
        } else {
            float4 v = ((const float4*)rmask)[rg];
            acc[16] = (v.x != 0.f ? 1.f : 0.f) + (v.y != 0.f ? 1.f : 0.f)
                    + (v.z != 0.f ? 1.f : 0.f) + (v.w != 0.f ? 1.f : 0.f);
        }
    }

    accum_pt(acc, w[0], p0.x, p0.y, p0.z, q0.x, q0.y, q0.z);
    accum_pt(acc, w[1], p0.w, p1.x, p1.y, q0.w, q1.x, q1.y);
    accum_pt(acc, w[2], p1.z, p1.w, p2.x, q1.z, q1.w, q2.x);
    accum_pt(acc, w[3], p2.y, p2.z, p2.w, q2.y, q2.z, q2.w);

    block_reduce<17>(acc, lds);
    if (threadIdx.x == 0) {
#pragma unroll
        for (int k = 0; k < 17; ++k) part[blk * PSTRIDE + k] = acc[k];
    }
}

// ---------------- pass B: closed-form 3x3 Kabsch per batch (f64) ----------------
__device__ __forceinline__ void normalize3(double* v) {
    double n = sqrt(v[0] * v[0] + v[1] * v[1] + v[2] * v[2]);
    if (n > 1e-300) { v[0] /= n; v[1] /= n; v[2] /= n; }
}
__device__ __forceinline__ void cross3(const double* a, const double* b, double* c) {
    c[0] = a[1] * b[2] - a[2] * b[1];
    c[1] = a[2] * b[0] - a[0] * b[2];
    c[2] = a[0] * b[1] - a[1] * b[0];
}
// M = (A - aI)(A - bI)
__device__ __forceinline__ void proj_mul(const double A[3][3], double a, double b, double M[3][3]) {
    double X[3][3], Y[3][3];
#pragma unroll
    for (int i = 0; i < 3; ++i)
#pragma unroll
        for (int j = 0; j < 3; ++j) {
            X[i][j] = A[i][j] - (i == j ? a : 0.0);
            Y[i][j] = A[i][j] - (i == j ? b : 0.0);
        }
#pragma unroll
    for (int i = 0; i < 3; ++i)
#pragma unroll
        for (int j = 0; j < 3; ++j)
            M[i][j] = X[i][0] * Y[0][j] + X[i][1] * Y[1][j] + X[i][2] * Y[2][j];
}
__device__ __forceinline__ void best_col(const double M[3][3], double v[3]) {
    double n0 = M[0][0]*M[0][0] + M[1][0]*M[1][0] + M[2][0]*M[2][0];
    double n1 = M[0][1]*M[0][1] + M[1][1]*M[1][1] + M[2][1]*M[2][1];
    double n2 = M[0][2]*M[0][2] + M[1][2]*M[1][2] + M[2][2]*M[2][2];
    int j = (n0 >= n1 && n0 >= n2) ? 0 : (n1 >= n2 ? 1 : 2);
    v[0] = M[0][j]; v[1] = M[1][j]; v[2] = M[2][j];
}

__device__ void kabsch_params(const float* s, float* o) {
    double cnt = (double)s[0];
    double cs = fmax(cnt, 1.0);
    double mup[3], muq[3];
#pragma unroll
    for (int i = 0; i < 3; ++i) { mup[i] = (double)s[1 + i] / cs; muq[i] = (double)s[4 + i] / cs; }
    double Hm[3][3];
#pragma unroll
    for (int i = 0; i < 3; ++i)
#pragma unroll
        for (int j = 0; j < 3; ++j)
            Hm[i][j] = (double)s[7 + 3 * i + j] - cnt * mup[i] * muq[j];

    // A = H^T H (symmetric PSD)
    double A[3][3];
#pragma unroll
    for (int i = 0; i < 3; ++i)
#pragma unroll
        for (int j = 0; j < 3; ++j)
            A[i][j] = Hm[0][i] * Hm[0][j] + Hm[1][i] * Hm[1][j] + Hm[2][i] * Hm[2][j];

    // closed-form eigenvalues (descending), trig method
    double q3 = (A[0][0] + A[1][1] + A[2][2]) / 3.0;
    double pp1 = A[0][1]*A[0][1] + A[0][2]*A[0][2] + A[1][2]*A[1][2];
    double d0m = A[0][0]-q3, d1m = A[1][1]-q3, d2m = A[2][2]-q3;
    double pp2 = d0m*d0m + d1m*d1m + d2m*d2m + 2.0*pp1;
    double lam[3];
    double v1[3], v2[3], v3[3];
    if (pp2 <= 1e-24 * (q3*q3) + 1e-290) {
        lam[0] = lam[1] = lam[2] = q3;
        v1[0]=1; v1[1]=0; v1[2]=0;
        v2[0]=0; v2[1]=1; v2[2]=0;
        v3[0]=0; v3[1]=0; v3[2]=1;
    } else {
        double p = sqrt(pp2 / 6.0), invp = 1.0 / p;
        double B[3][3];
#pragma unroll
        for (int i = 0; i < 3; ++i)
#pragma unroll
            for (int j = 0; j < 3; ++j)
                B[i][j] = (A[i][j] - (i == j ? q3 : 0.0)) * invp;
        double detB = B[0][0]*(B[1][1]*B[2][2]-B[1][2]*B[2][1])
                    - B[0][1]*(B[1][0]*B[2][2]-B[1][2]*B[2][0])
                    + B[0][2]*(B[1][0]*B[2][1]-B[1][1]*B[2][0]);
        double r = detB * 0.5;
        r = fmin(1.0, fmax(-1.0, r));
        double phi = acos(r) / 3.0;
        lam[0] = q3 + 2.0 * p * cos(phi);
        lam[2] = q3 + 2.0 * p * cos(phi + 2.0943951023931953);  // +2pi/3
        lam[1] = 3.0 * q3 - lam[0] - lam[2];

        // v1: largest-eigval vector from projector (A-l1 I)(A-l2 I)
        double M[3][3];
        proj_mul(A, lam[1], lam[2], M);
        best_col(M, v1);
        double n1v = sqrt(v1[0]*v1[0] + v1[1]*v1[1] + v1[2]*v1[2]);
        if (n1v > 1e-150) { v1[0]/=n1v; v1[1]/=n1v; v1[2]/=n1v; }
        else { v1[0]=1; v1[1]=0; v1[2]=0; }
        // v3: smallest-eigval vector
        proj_mul(A, lam[0], lam[1], M);
        best_col(M, v3);
        double dot13 = v3[0]*v1[0] + v3[1]*v1[1] + v3[2]*v1[2];
        v3[0] -= dot13 * v1[0]; v3[1] -= dot13 * v1[1]; v3[2] -= dot13 * v1[2];
        double n3v = sqrt(v3[0]*v3[0] + v3[1]*v3[1] + v3[2]*v3[2]);
        if (n3v > 1e-150) { v3[0]/=n3v; v3[1]/=n3v; v3[2]/=n3v; }
        else {
            double a0 = fabs(v1[0]), a1 = fabs(v1[1]), a2 = fabs(v1[2]);
            double ax[3] = {0, 0, 0};
            if (a0 <= a1 && a0 <= a2) ax[0] = 1; else if (a1 <= a2) ax[1] = 1; else ax[2] = 1;
            double dd = ax[0]*v1[0] + ax[1]*v1[1] + ax[2]*v1[2];
            v3[0] = ax[0] - dd*v1[0]; v3[1] = ax[1] - dd*v1[1]; v3[2] = ax[2] - dd*v1[2];
            normalize3(v3);
        }
        cross3(v3, v1, v2);   // v1 x v2 = v3: right-handed orthonormal
    }

    double Vs[3][3];
#pragma unroll
    for (int i = 0; i < 3; ++i) { Vs[i][0] = v1[i]; Vs[i][1] = v2[i]; Vs[i][2] = v3[i]; }
    double sv[3];
#pragma unroll
    for (int k = 0; k < 3; ++k) sv[k] = sqrt(fmax(lam[k], 0.0));

    // U columns: u_k = H v_k / s_k with degeneracy guards
    double U[3][3];
    double eps = sv[0] * 1e-12 + 1e-300;
    for (int k = 0; k < 3; ++k) {
        double hv[3];
        for (int i = 0; i < 3; ++i)
            hv[i] = Hm[i][0] * Vs[0][k] + Hm[i][1] * Vs[1][k] + Hm[i][2] * Vs[2][k];
        if (sv[k] > eps) {
            double col[3] = {hv[0] / sv[k], hv[1] / sv[k], hv[2] / sv[k]};
            normalize3(col);
            for (int i = 0; i < 3; ++i) U[i][k] = col[i];
        } else if (k == 0) {
            U[0][0] = 1; U[1][0] = 0; U[2][0] = 0;
        } else if (k == 1) {
            double u0[3] = {U[0][0], U[1][0], U[2][0]};
            double ax[3] = {0, 0, 0};
            double a0 = fabs(u0[0]), a1 = fabs(u0[1]), a2 = fabs(u0[2]);
            if (a0 <= a1 && a0 <= a2) ax[0] = 1; else if (a1 <= a2) ax[1] = 1; else ax[2] = 1;
            double col[3]; cross3(u0, ax, col); normalize3(col);
            for (int i = 0; i < 3; ++i) U[i][1] = col[i];
        } else {
            double u0[3] = {U[0][0], U[1][0], U[2][0]};
            double u1[3] = {U[0][1], U[1][1], U[2][1]};
            double col[3]; cross3(u0, u1, col); normalize3(col);
            for (int i = 0; i < 3; ++i) U[i][2] = col[i];
        }
    }

    double detH = Hm[0][0] * (Hm[1][1] * Hm[2][2] - Hm[1][2] * Hm[2][1])
                - Hm[0][1] * (Hm[1][0] * Hm[2][2] - Hm[1][2] * Hm[2][0])
                + Hm[0][2] * (Hm[1][0] * Hm[2][1] - Hm[1][1] * Hm[2][0]);
    double e2 = (detH > 0.0) ? 1.0 : ((detH < 0.0) ? -1.0 : 0.0);

    // R = Vs * diag(1,1,e2) * U^T
#pragma unroll
    for (int i = 0; i < 3; ++i)
#pragma unroll
        for (int j = 0; j < 3; ++j)
            o[3 * i + j] = (float)(Vs[i][0] * U[j][0] + Vs[i][1] * U[j][1] + e2 * Vs[i][2] * U[j][2]);

    double n = (double)s[16];
    double d0 = 1.24 * cbrt(fmax(n - 15.0, 1e-3)) - 1.8;
    d0 = fmax(d0, 1e-3);
#pragma unroll
    for (int i = 0; i < 3; ++i) { o[9 + i] = (float)mup[i]; o[12 + i] = (float)muq[i]; }
    o[15] = (float)(1.0 / (d0 * d0));
    o[16] = (float)cnt;
}

__global__ __launch_bounds__(128) void k_solve(
    const float* __restrict__ part, float* __restrict__ params) {
    int b = blockIdx.x * 128 + threadIdx.x;
    if (b >= BATCH) return;
    float s[17];
#pragma unroll
    for (int k = 0; k < 17; ++k)
        s[k] = part[(3 * b + 0) * PSTRIDE + k]
             + part[(3 * b + 1) * PSTRIDE + k]
             + part[(3 * b + 2) * PSTRIDE + k];
    kabsch_params(s, params + (size_t)b * PSTRIDE);
}

// ---------------- pass C: rotate + TM partial sums ----------------
__global__ __launch_bounds__(TPB) void k_tmC(
    const float* __restrict__ P, const float* __restrict__ Q,
    const void* __restrict__ cmask,
    const float* __restrict__ params, float* __restrict__ tmp) {
    int blk = blockIdx.x;
    int b = blk / SLICES, slice = blk % SLICES;
    __shared__ int slds[9];
    __shared__ float lds[NWAVE];
    int flag = detect_flag(cmask, slds);

    const float* pr = params + (size_t)b * PSTRIDE;
    float R0 = pr[0], R1 = pr[1], R2 = pr[2];
    float R3 = pr[3], R4 = pr[4], R5 = pr[5];
    float R6 = pr[6], R7 = pr[7], R8 = pr[8];
    float mpx = pr[9], mpy = pr[10], mpz = pr[11];
    float mqx = pr[12], mqy = pr[13], mqz = pr[14];
    float inv = pr[15];

    const float4* Pv = (const float4*)(P + (size_t)b * NFLT);
    const float4* Qv = (const float4*)(Q + (size_t)b * NFLT);
    int g = slice * GPS + threadIdx.x;

    float4 p0 = Pv[3 * g + 0], p1 = Pv[3 * g + 1], p2 = Pv[3 * g + 2];
    float4 q0 = Qv[3 * g + 0], q1 = Qv[3 * g + 1], q2 = Qv[3 * g + 2];
    float w[4];
    load_mask4(cmask, flag, (size_t)b * NGRP + g, w);

    float px[4] = {p0.x, p0.w, p1.z, p2.y};
    float py[4] = {p0.y, p1.x, p1.w, p2.z};
    float pz[4] = {p0.z, p1.y, p2.x, p2.w};
    float qx[4] = {q0.x, q0.w, q1.z, q2.y};
    float qy[4] = {q0.y, q1.x, q1.w, q2.z};
    float qz[4] = {q0.z, q1.y, q2.x, q2.w};

    float acc[1] = {0.0f};
#pragma unroll
    for (int u = 0; u < 4; ++u) {
        float pcx = px[u] - mpx, pcy = py[u] - mpy, pcz = pz[u] - mpz;
        float ax = R0 * pcx + R1 * pcy + R2 * pcz;
        float ay = R3 * pcx + R4 * pcy + R5 * pcz;
        float az = R6 * pcx + R7 * pcy + R8 * pcz;
        float dx = ax - (qx[u] - mqx);
        float dy = ay - (qy[u] - mqy);
        float dz = az - (qz[u] - mqz);
        float d2 = dx * dx + dy * dy + dz * dz;
        acc[0] += w[u] / (1.0f + d2 * inv);
    }
    block_reduce<1>(acc, lds);
    if (threadIdx.x == 0) tmp[blk] = acc[0];
}

// ---------------- pass D: combine ----------------
__global__ __launch_bounds__(128) void k_final(
    const float* __restrict__ tmp, const float* __restrict__ params,
    float* __restrict__ out) {
    int b = blockIdx.x * 128 + threadIdx.x;
    if (b >= BATCH) return;
    float cnt = params[(size_t)b * PSTRIDE + 16];
    float s = tmp[3 * b + 0] + tmp[3 * b + 1] + tmp[3 * b + 2];
    out[b] = (cnt > 0.0f) ? s / fmaxf(cnt, 1.0f) : 0.0f;
}

// ---------------- launcher ----------------
extern "C" void kernel_launch(void* const* d_in, const int* in_sizes, int n_in,
                              void* d_out, int out_size, void* d_ws, size_t ws_size,
                              hipStream_t stream) {
    const float* P = (const float*)d_in[0];
    const float* Q = (const float*)d_in[1];
    const void* cm = d_in[2];
    const void* rm = d_in[3];
    float* out = (float*)d_out;

    float* part   = (float*)d_ws;                          // 1536*20 floats
    float* params = part + (size_t)BATCH * SLICES * PSTRIDE;  // 512*20 floats
    float* tmp    = params + (size_t)BATCH * PSTRIDE;         // 1536 floats

    k_sumsA<<<BATCH * SLICES, TPB, 0, stream>>>(P, Q, cm, rm, part);
    k_solve<<<(BATCH + 127) / 128, 128, 0, stream>>>(part, params);
    k_tmC<<<BATCH * SLICES, TPB, 0, stream>>>(P, Q, cm, params, tmp);
    k_final<<<(BATCH + 127) / 128, 128, 0, stream>>>(tmp, params, out);
}